// Round 4
// baseline (288.621 us; speedup 1.0000x reference)
//
#include <hip/hip_runtime.h>
#include <stdint.h>

// Conv2DUF: 3x3 s1 p1 conv, x[32][128][56][56] f32, weight[1152][256] f32
// (k = c*9 + kh*3 + kw), bias[256] f32 -> out[32][256][56][56] f32.
// bf16 implicit GEMM: M = 32*56*56 = 100352, N = 256, K = 1152.
//  ws: xt = bf16 x padded+transposed [B][58][58][128] (NHWC, halo=0)
//      wt = bf16 weight reordered    [9][256][128]    (K-contiguous)
// R3: software-pipelined K-loop: BK=32, 3 LDS buffers, 2-deep prefetch,
//     one raw s_barrier/step, vmcnt(6) waits (never drain in-flight prefetch).
//     K-major LDS granule layout -> conflict-free staging AND fragment reads.

#define C_INQ 128
#define C_OUTQ 256
#define HDIM 56
#define WDIM 56
#define BDIM 32
#define HP 58
#define WP 58
#define HWPIX (HDIM * WDIM)          // 3136
#define XT_ELEMS ((size_t)BDIM * HP * WP * C_INQ)   // 13,778,944
#define XT_BYTES (XT_ELEMS * 2)                     // 27,557,888

typedef __bf16 bf16x8 __attribute__((ext_vector_type(8)));
typedef unsigned short ushort8 __attribute__((ext_vector_type(8)));
typedef float floatx4 __attribute__((ext_vector_type(4)));

__device__ __forceinline__ unsigned short f2bf(float f) {
  union { float f; unsigned int u; } v; v.f = f;
  unsigned int u = v.u;
  unsigned int r = u + 0x7FFFu + ((u >> 16) & 1u);   // RNE (finite inputs)
  return (unsigned short)(r >> 16);
}
__device__ __forceinline__ unsigned int pack2(float a, float b) {
  return (unsigned int)f2bf(a) | ((unsigned int)f2bf(b) << 16);
}

// ---------------- kernel 1: x NCHW f32 -> xt [B][58][58][128] bf16, zero halo
__global__ __launch_bounds__(256) void pad_transpose_kernel(
    const float* __restrict__ x, unsigned short* __restrict__ xt) {
  const int blk = blockIdx.x;           // B*HP = 1856 blocks
  const int b = blk / HP;
  const int hp = blk % HP;
  const int t = threadIdx.x;
  uint4* __restrict__ xtrow4 = (uint4*)(xt + (size_t)(b * HP + hp) * (WP * C_INQ));
  if (hp == 0 || hp == HP - 1) {        // halo rows: 928 uint4 of zeros
    for (int i = t; i < 928; i += 256) xtrow4[i] = make_uint4(0, 0, 0, 0);
    return;
  }
  __shared__ float lds[C_INQ * 62];     // [c][w], stride 62
  const int h = hp - 1;
  const float* __restrict__ xb = x + (size_t)b * C_INQ * HWPIX + (size_t)h * WDIM;
  for (int i = t; i < 1792; i += 256) { // 128 c * 14 float4 along w
    int c = i / 14, w4 = (i - c * 14) * 4;
    const float4 v = *(const float4*)(xb + (size_t)c * HWPIX + w4);
    float* d = lds + c * 62 + w4;
    *(float2*)d = make_float2(v.x, v.y);
    *(float2*)(d + 2) = make_float2(v.z, v.w);
  }
  __syncthreads();
  for (int j = t; j < 928; j += 256) {  // chunk j: wp = j>>4, c8 = (j&15)*8
    int wp = j >> 4, c8 = (j & 15) * 8;
    uint4 o;
    if (wp == 0 || wp == WP - 1) {
      o = make_uint4(0, 0, 0, 0);
    } else {
      const float* s = lds + c8 * 62 + (wp - 1);
      o.x = pack2(s[0],   s[62]);
      o.y = pack2(s[124], s[186]);
      o.z = pack2(s[248], s[310]);
      o.w = pack2(s[372], s[434]);
    }
    xtrow4[j] = o;
  }
}

// ---------------- kernel 2: weight [1152][256] f32 -> wt [9][256][128] bf16
__global__ __launch_bounds__(256) void weight_transform_kernel(
    const float* __restrict__ w, unsigned short* __restrict__ wt) {
  const int bx = blockIdx.x;
  const int khw = bx >> 4;
  const int r4 = bx & 15;
  const int n0w = (r4 >> 2) * 64;
  const int c32 = (r4 & 3) * 32;
  const int t = threadIdx.x;
  __shared__ float lds[32 * 66];        // [c][n], stride 66
#pragma unroll
  for (int r = 0; r < 8; ++r) {
    int idx = r * 256 + t;              // 32*64 = 2048
    int n = idx & 63, c = idx >> 6;
    lds[c * 66 + n] = w[(size_t)((c32 + c) * 9 + khw) * C_OUTQ + n0w + n];
  }
  __syncthreads();
  {
    int n = t >> 2, c8 = (t & 3) * 8;
    const float* s = lds + c8 * 66 + n;
    uint4 o;
    o.x = pack2(s[0],   s[66]);
    o.y = pack2(s[132], s[198]);
    o.z = pack2(s[264], s[330]);
    o.w = pack2(s[396], s[462]);
    *(uint4*)(wt + (size_t)khw * (C_OUTQ * C_INQ) + (size_t)(n0w + n) * C_INQ + c32 + c8) = o;
  }
}

// ---------------- kernel 3: implicit GEMM, 128x256 tile, BK=32, pipelined
#define BM 128
#define BN 256
#define BK 32
#define STEPS 36
#define NBUF 3

__device__ __forceinline__ void step_koff(int s, int& koffA, int& koffB) {
  const int khw = s >> 2;
  const int c0 = (s & 3) * 32;
  const int kh = khw / 3;
  const int kw = khw - kh * 3;
  koffA = (kh * WP + kw) * C_INQ + c0;
  koffB = khw * (C_OUTQ * C_INQ) + c0;
}

__global__ __launch_bounds__(256, 2) void conv_gemm_kernel(
    const unsigned short* __restrict__ xt,
    const unsigned short* __restrict__ wt,
    const float* __restrict__ bias,
    float* __restrict__ out) {
  // K-major granule layout (granule = 16B = 8 bf16):
  //   bufA slot g: kpart = g>>7, row = g&127   (4 kparts x 128 rows, 8KB)
  //   bufB slot g: kpart = g>>8, n   = g&255   (4 kparts x 256 n,    16KB)
  __shared__ __align__(16) unsigned short ldsA[NBUF][BM * BK];
  __shared__ __align__(16) unsigned short ldsB[NBUF][BN * BK];

  const int t = threadIdx.x;
  const int lane = t & 63;
  const int wave = t >> 6;
  const int tile_m = blockIdx.x;    // 784

  // staging sources. A: thread t stages slots {t, 256+t}: row = t&127 both,
  // kpart = 2r + (t>>7). B: slots {r*256+t}: n = t, kpart = r.
  int pixbaseA;
  {
    int row = t & 127;
    int pix = tile_m * BM + row;
    int b = pix / HWPIX;
    int p = pix - b * HWPIX;
    int h = p / WDIM;
    int w = p - h * WDIM;
    pixbaseA = ((b * HP + h) * WP + w) * C_INQ;
  }
  const int kA0 = (t >> 7) * 8;            // kpart offset for r=0 (elems)
  const int srcB0 = t * C_INQ;             // n*C_INQ
  // wave-uniform LDS dest slot bases (HW adds lane*16B)
  const int dstA0 = (wave * 64) * 8;       // r=0 slot base in ushorts
  const int dstA1 = (256 + wave * 64) * 8;
  const int dstB[4] = { (wave * 64) * 8, (256 + wave * 64) * 8,
                        (512 + wave * 64) * 8, (768 + wave * 64) * 8 };

#define STAGE(buf, koffA_, koffB_)                                             \
  do {                                                                         \
    __builtin_amdgcn_global_load_lds(                                          \
        (const __attribute__((address_space(1))) unsigned int*)(xt + pixbaseA + kA0 + (koffA_)), \
        (__attribute__((address_space(3))) unsigned int*)(&ldsA[buf][0] + dstA0), 16, 0, 0); \
    __builtin_amdgcn_global_load_lds(                                          \
        (const __attribute__((address_space(1))) unsigned int*)(xt + pixbaseA + kA0 + 16 + (koffA_)), \
        (__attribute__((address_space(3))) unsigned int*)(&ldsA[buf][0] + dstA1), 16, 0, 0); \
    _Pragma("unroll")                                                          \
    for (int r = 0; r < 4; ++r)                                                \
      __builtin_amdgcn_global_load_lds(                                        \
          (const __attribute__((address_space(1))) unsigned int*)(wt + srcB0 + r * 8 + (koffB_)), \
          (__attribute__((address_space(3))) unsigned int*)(&ldsB[buf][0] + dstB[r]), 16, 0, 0); \
  } while (0)

  // fragment geometry: wave grid 2x2 -> wave tile 64m x 128n
  const int wm = (wave >> 1) * 64;
  const int wn = (wave & 1) * 128;
  const int mrow = lane & 15;
  const int quad = lane >> 4;

  floatx4 acc[4][8] = {};

  // prologue: prefetch tiles 0 and 1
  {
    int ka, kb;
    step_koff(0, ka, kb);
    STAGE(0, ka, kb);
    step_koff(1, ka, kb);
    STAGE(1, ka, kb);
  }

  for (int s = 0; s < STEPS; ++s) {
    // wait for tile-s loads (oldest 6) WITHOUT draining the in-flight
    // prefetch of tile s+1; then barrier so all waves' tile-s data is valid.
    if (s == STEPS - 1) asm volatile("s_waitcnt vmcnt(0)" ::: "memory");
    else                asm volatile("s_waitcnt vmcnt(6)" ::: "memory");
    __builtin_amdgcn_s_barrier();
    asm volatile("" ::: "memory");
    if (s < STEPS - 2) {                   // prefetch tile s+2
      int ka, kb;
      step_koff(s + 2, ka, kb);
      STAGE((s + 2) % NBUF, ka, kb);
    }
    const unsigned short* __restrict__ bufA = &ldsA[s % NBUF][0];
    const unsigned short* __restrict__ bufB = &ldsB[s % NBUF][0];
    bf16x8 afr[4], bfr[8];
#pragma unroll
    for (int i = 0; i < 4; ++i)
      afr[i] = __builtin_bit_cast(bf16x8,
               *(const ushort8*)(bufA + ((quad << 7) + wm + i * 16 + mrow) * 8));
#pragma unroll
    for (int jn = 0; jn < 8; ++jn)
      bfr[jn] = __builtin_bit_cast(bf16x8,
                *(const ushort8*)(bufB + ((quad << 8) + wn + jn * 16 + mrow) * 8));
#pragma unroll
    for (int i = 0; i < 4; ++i)
#pragma unroll
      for (int jn = 0; jn < 8; ++jn)
        acc[i][jn] = __builtin_amdgcn_mfma_f32_16x16x32_bf16(afr[i], bfr[jn], acc[i][jn], 0, 0, 0);
  }

  // epilogue: C/D layout col(n) = lane&15, row(m) = quad*4 + reg.
  float bv[8];
#pragma unroll
  for (int jn = 0; jn < 8; ++jn) bv[jn] = bias[wn + jn * 16 + mrow];
#pragma unroll
  for (int i = 0; i < 4; ++i) {
    const int mbase = tile_m * BM + wm + i * 16 + quad * 4;
    const int b = mbase / HWPIX;
    const int p = mbase - b * HWPIX;
    float* obase = out + (size_t)b * (C_OUTQ * HWPIX) + p;
#pragma unroll
    for (int jn = 0; jn < 8; ++jn) {
      const int ng = wn + jn * 16 + mrow;
      floatx4 v = acc[i][jn];
      v[0] += bv[jn]; v[1] += bv[jn]; v[2] += bv[jn]; v[3] += bv[jn];
      *(floatx4*)(obase + (size_t)ng * HWPIX) = v;
    }
  }
}

extern "C" void kernel_launch(void* const* d_in, const int* in_sizes, int n_in,
                              void* d_out, int out_size, void* d_ws, size_t ws_size,
                              hipStream_t stream) {
  const float* x    = (const float*)d_in[0];
  const float* w    = (const float*)d_in[1];
  const float* bias = (const float*)d_in[2];
  float* out = (float*)d_out;

  unsigned short* xt = (unsigned short*)d_ws;
  unsigned short* wt = (unsigned short*)((char*)d_ws + XT_BYTES);  // +589,824 B

  hipLaunchKernelGGL(pad_transpose_kernel, dim3(BDIM * HP), dim3(256), 0, stream, x, xt);
  hipLaunchKernelGGL(weight_transform_kernel, dim3(144), dim3(256), 0, stream, w, wt);
  hipLaunchKernelGGL(conv_gemm_kernel, dim3(784), dim3(256), 0, stream, xt, wt, bias, out);
}